// Round 2
// baseline (1127.637 us; speedup 1.0000x reference)
//
#include <hip/hip_runtime.h>

#define NN 100000

// ---------- bf16 helpers ----------
__device__ __forceinline__ float bf2f(unsigned short u) {
    union { unsigned int i; float f; } v;
    v.i = ((unsigned int)u) << 16;
    return v.f;
}
__device__ __forceinline__ unsigned short f2bf(float f) {
    unsigned int u = __float_as_uint(f);
    unsigned int r = u + 0x7fffu + ((u >> 16) & 1u);  // RNE
    return (unsigned short)(r >> 16);
}

// dtype-flag-driven loads: flags[0]=1 -> floats are bf16, else fp32
__device__ __forceinline__ float ldf(const void* p, int i, int bf) {
    return bf ? bf2f(((const unsigned short*)p)[i]) : ((const float*)p)[i];
}
// flags[1]=1 -> edge_index is int64, else int32
__device__ __forceinline__ int lde(const void* p, int i, int i64f) {
    return i64f ? (int)((const long long*)p)[i] : ((const int*)p)[i];
}

// ---------- dtype detection (single thread) ----------
__global__ void detect_kernel(const unsigned int* __restrict__ xw,
                              const unsigned int* __restrict__ eiw,
                              int* __restrict__ flags) {
    if (threadIdx.x == 0 && blockIdx.x == 0) {
        // float dtype: exponent field of LOW 16 bits of each 32-bit word, read as bf16.
        // bf16 N(0,1) data -> concentrated in [100,130]; fp32 data -> uniform mantissa bits.
        int outliers = 0;
        for (int i = 0; i < 128; ++i) {
            unsigned int w = xw[i];
            int e = (int)((w >> 7) & 0xFFu);
            if (e < 100 || e > 130) outliers++;
        }
        flags[0] = (outliers < 16) ? 1 : 0;
        // index dtype: odd 32-bit words all zero iff int64 (values < 2^31)
        int zeros = 0;
        for (int i = 0; i < 64; ++i)
            if (eiw[2 * i + 1] == 0u) zeros++;
        flags[1] = (zeros >= 48) ? 1 : 0;
    }
}

// ---------- tiny kernels ----------
__global__ void zero_int_kernel(int* __restrict__ p, int n) {
    int i = blockIdx.x * blockDim.x + threadIdx.x;
    if (i < n) p[i] = 0;
}

__global__ void hist_kernel(const void* __restrict__ ei, int E, int* __restrict__ deg,
                            const int* __restrict__ flags) {
    int e = blockIdx.x * blockDim.x + threadIdx.x;
    int i64f = flags[1];
    if (e < E) {
        int c = lde(ei, E + e, i64f);
        c = min(max(c, 0), NN - 1);  // insurance against misdetection
        atomicAdd(&deg[c], 1);
    }
}

__global__ void dinv_kernel(const int* __restrict__ deg, float* __restrict__ dinv, int n) {
    int i = blockIdx.x * blockDim.x + threadIdx.x;
    if (i < n) dinv[i] = rsqrtf((float)(deg[i] + 1));  // +1 self-loop; always >= 1
}

// single-block scan over n degrees -> exclusive offsets (and cursor copy)
__global__ void scan_kernel(const int* __restrict__ deg, int* __restrict__ off,
                            int* __restrict__ cur, int n) {
    __shared__ int s[256];
    int tid = threadIdx.x;
    int carry = 0;
    for (int base = 0; base < n; base += 1024) {
        int idx = base + tid * 4;
        int v0 = (idx + 0 < n) ? deg[idx + 0] : 0;
        int v1 = (idx + 1 < n) ? deg[idx + 1] : 0;
        int v2 = (idx + 2 < n) ? deg[idx + 2] : 0;
        int v3 = (idx + 3 < n) ? deg[idx + 3] : 0;
        int tsum = v0 + v1 + v2 + v3;
        s[tid] = tsum;
        __syncthreads();
        for (int o = 1; o < 256; o <<= 1) {
            int t = (tid >= o) ? s[tid - o] : 0;
            __syncthreads();
            s[tid] += t;
            __syncthreads();
        }
        int excl = s[tid] - tsum;
        int total = s[255];
        int p = carry + excl;
        if (idx + 0 < n) { off[idx + 0] = p; cur[idx + 0] = p; } p += v0;
        if (idx + 1 < n) { off[idx + 1] = p; cur[idx + 1] = p; } p += v1;
        if (idx + 2 < n) { off[idx + 2] = p; cur[idx + 2] = p; } p += v2;
        if (idx + 3 < n) { off[idx + 3] = p; cur[idx + 3] = p; } p += v3;
        carry += total;
        __syncthreads();
    }
    if (tid == 0) off[n] = carry;
}

__global__ void scatter_kernel(const void* __restrict__ ei, const float* __restrict__ dinv,
                               int* __restrict__ cur, int* __restrict__ esrc,
                               float* __restrict__ ew, int E, const int* __restrict__ flags) {
    int e = blockIdx.x * blockDim.x + threadIdx.x;
    int i64f = flags[1];
    if (e < E) {
        int r = lde(ei, e, i64f);
        int c = lde(ei, E + e, i64f);
        r = min(max(r, 0), NN - 1);
        c = min(max(c, 0), NN - 1);
        int pos = atomicAdd(&cur[c], 1);
        esrc[pos] = r;
        ew[pos] = dinv[r] * dinv[c];
    }
}

// ---------- GEMM1: h1[N,128](bf16) = X[N,256] @ W1[256,128], fp32 accum ----------
__global__ __launch_bounds__(256) void gemm1_kernel(const void* __restrict__ x,
                                                    const void* __restrict__ W,
                                                    unsigned short* __restrict__ h,
                                                    const int* __restrict__ flags) {
    __shared__ float xs[16 * 256];  // 16 KB
    __shared__ float ws[64 * 128];  // 32 KB
    int bf = flags[0];
    int tid = threadIdx.x;
    int node0 = blockIdx.x * 16;  // 100000 = 6250*16 exactly
    for (int j = 0; j < 16; ++j) {
        int f = j * 256 + tid;
        xs[f] = ldf(x, node0 * 256 + f, bf);
    }
    int grp = tid >> 6;         // 0..3 -> 4 nodes each
    int col2 = (tid & 63) * 2;  // 0,2,...,126
    float acc[4][2] = {};
    for (int kb = 0; kb < 256; kb += 64) {
        for (int j = 0; j < 32; ++j) {
            int f = j * 256 + tid;
            ws[f] = ldf(W, kb * 128 + f, bf);
        }
        __syncthreads();
        for (int k = 0; k < 64; ++k) {
            float2 w = *(const float2*)&ws[k * 128 + col2];
#pragma unroll
            for (int m = 0; m < 4; ++m) {
                float xv = xs[(grp * 4 + m) * 256 + kb + k];
                acc[m][0] = fmaf(xv, w.x, acc[m][0]);
                acc[m][1] = fmaf(xv, w.y, acc[m][1]);
            }
        }
        __syncthreads();
    }
#pragma unroll
    for (int m = 0; m < 4; ++m) {
        int node = node0 + grp * 4 + m;
        ushort2 v = make_ushort2(f2bf(acc[m][0]), f2bf(acc[m][1]));
        *(ushort2*)&h[node * 128 + col2] = v;
    }
}

// ---------- aggregation (bf16 in/out): out[c] = h[c]*dinv[c]^2 + sum_in h[r]*w ----------
template <int F>
__global__ void agg_kernel(const unsigned short* __restrict__ h, const float* __restrict__ dinv,
                           const int* __restrict__ off, const int* __restrict__ esrc,
                           const float* __restrict__ ew, unsigned short* __restrict__ outp) {
    int c = blockIdx.x;
    int f = threadIdx.x;
    float dc = dinv[c];
    float acc = bf2f(h[c * F + f]) * dc * dc;
    int e = off[c + 1];
    for (int j = off[c]; j < e; ++j)
        acc = fmaf(bf2f(h[esrc[j] * F + f]), ew[j], acc);
    outp[c * F + f] = f2bf(acc);
}

// ---------- GEMM2: h2[N,64](bf16) = relu(agg1+b1)[N,128] @ W2[128,64] ----------
__global__ __launch_bounds__(256) void gemm2_kernel(const unsigned short* __restrict__ a,
                                                    const void* __restrict__ W,
                                                    const void* __restrict__ b1,
                                                    unsigned short* __restrict__ h2,
                                                    const int* __restrict__ flags) {
    __shared__ float xs[16 * 128];  // 8 KB
    __shared__ float ws[128 * 64];  // 32 KB
    int bf = flags[0];
    int tid = threadIdx.x;
    int node0 = blockIdx.x * 16;
    for (int j = 0; j < 32; ++j) {
        int f = j * 256 + tid;
        ws[f] = ldf(W, f, bf);
    }
    for (int j = 0; j < 8; ++j) {
        int f = j * 256 + tid;
        int node = f >> 7, c = f & 127;
        float v = bf2f(a[(node0 + node) * 128 + c]) + ldf(b1, c, bf);
        xs[f] = fmaxf(v, 0.f);
    }
    __syncthreads();
    int col = tid & 63, grp = tid >> 6;
    float acc[4] = {};
    for (int k = 0; k < 128; ++k) {
        float w = ws[k * 64 + col];
#pragma unroll
        for (int m = 0; m < 4; ++m)
            acc[m] = fmaf(xs[(grp * 4 + m) * 128 + k], w, acc[m]);
    }
#pragma unroll
    for (int m = 0; m < 4; ++m)
        h2[(node0 + grp * 4 + m) * 64 + col] = f2bf(acc[m]);
}

// ---------- final aggregation fused with +b2 and output store (dual dtype out) ----------
__global__ void agg_out_kernel(const unsigned short* __restrict__ h, const float* __restrict__ dinv,
                               const int* __restrict__ off, const int* __restrict__ esrc,
                               const float* __restrict__ ew, const void* __restrict__ b2,
                               void* __restrict__ outp, const int* __restrict__ flags) {
    int c = blockIdx.x;
    int f = threadIdx.x;
    int bf = flags[0];
    float dc = dinv[c];
    float acc = bf2f(h[c * 64 + f]) * dc * dc;
    int e = off[c + 1];
    for (int j = off[c]; j < e; ++j)
        acc = fmaf(bf2f(h[esrc[j] * 64 + f]), ew[j], acc);
    acc += ldf(b2, f, bf);
    if (bf) ((unsigned short*)outp)[c * 64 + f] = f2bf(acc);
    else    ((float*)outp)[c * 64 + f] = acc;
}

extern "C" void kernel_launch(void* const* d_in, const int* in_sizes, int n_in,
                              void* d_out, int out_size, void* d_ws, size_t ws_size,
                              hipStream_t stream) {
    const void* x  = d_in[0];
    const void* ei = d_in[1];
    const void* W1 = d_in[2];
    const void* b1 = d_in[3];
    const void* W2 = d_in[4];
    const void* b2 = d_in[5];

    const int N = NN;
    const int E = in_sizes[1] / 2;

    // workspace layout, 256B-aligned, ~66 MB total
    char* ws = (char*)d_ws;
    size_t o = 0;
    auto alloc = [&](size_t bytes) { size_t r = o; o += (bytes + 255) & ~(size_t)255; return r; };
    int*   flags = (int*)(ws + alloc(256));
    int*   deg   = (int*)(ws + alloc((size_t)N * 4));
    float* dinv  = (float*)(ws + alloc((size_t)N * 4));
    int*   off   = (int*)(ws + alloc((size_t)(N + 1) * 4));
    int*   cur   = (int*)(ws + alloc((size_t)N * 4));
    int*   esrc  = (int*)(ws + alloc((size_t)E * 4));
    float* ew    = (float*)(ws + alloc((size_t)E * 4));
    unsigned short* h1   = (unsigned short*)(ws + alloc((size_t)N * 128 * 2));
    unsigned short* agg1 = (unsigned short*)(ws + alloc((size_t)N * 128 * 2));
    unsigned short* h2   = h1;  // reuse (h1 dead after agg<128>)

    detect_kernel<<<1, 1, 0, stream>>>((const unsigned int*)x, (const unsigned int*)ei, flags);
    zero_int_kernel<<<(N + 255) / 256, 256, 0, stream>>>(deg, N);
    hist_kernel<<<(E + 255) / 256, 256, 0, stream>>>(ei, E, deg, flags);
    dinv_kernel<<<(N + 255) / 256, 256, 0, stream>>>(deg, dinv, N);
    scan_kernel<<<1, 256, 0, stream>>>(deg, off, cur, N);
    scatter_kernel<<<(E + 255) / 256, 256, 0, stream>>>(ei, dinv, cur, esrc, ew, E, flags);

    gemm1_kernel<<<N / 16, 256, 0, stream>>>(x, W1, h1, flags);
    agg_kernel<128><<<N, 128, 0, stream>>>(h1, dinv, off, esrc, ew, agg1);
    gemm2_kernel<<<N / 16, 256, 0, stream>>>(agg1, W2, b1, h2, flags);
    agg_out_kernel<<<N, 64, 0, stream>>>(h2, dinv, off, esrc, ew, b2, d_out, flags);
}

// Round 4
// 663.566 us; speedup vs baseline: 1.6994x; 1.6994x over previous
//
#include <hip/hip_runtime.h>

#define NN 100000

typedef __attribute__((ext_vector_type(8))) short short8;
typedef __attribute__((ext_vector_type(4))) float f32x4;

// ---------- bf16 helpers ----------
__device__ __forceinline__ float bf2f(unsigned short u) {
    union { unsigned int i; float f; } v;
    v.i = ((unsigned int)u) << 16;
    return v.f;
}
__device__ __forceinline__ unsigned short f2bf(float f) {
    unsigned int u = __float_as_uint(f);
    unsigned int r = u + 0x7fffu + ((u >> 16) & 1u);  // RNE
    return (unsigned short)(r >> 16);
}
// flags[0]=1 -> float tensors are bf16, else fp32
__device__ __forceinline__ float ldf(const void* p, int i, int bf) {
    return bf ? bf2f(((const unsigned short*)p)[i]) : ((const float*)p)[i];
}
// flags[1]=1 -> edge_index is int64, else int32
__device__ __forceinline__ int lde(const void* p, int i, int i64f) {
    return i64f ? (int)((const long long*)p)[i] : ((const int*)p)[i];
}
// load 8 consecutive float-typed input elements as bf16 short8 (flag-driven)
__device__ __forceinline__ short8 ld8bf(const void* p, size_t i, int bf) {
    if (bf) return *(const short8*)((const unsigned short*)p + i);
    const float* f = (const float*)p + i;
    f32x4 a = *(const f32x4*)f;
    f32x4 b = *(const f32x4*)(f + 4);
    short8 o;
    o[0] = (short)f2bf(a[0]); o[1] = (short)f2bf(a[1]);
    o[2] = (short)f2bf(a[2]); o[3] = (short)f2bf(a[3]);
    o[4] = (short)f2bf(b[0]); o[5] = (short)f2bf(b[1]);
    o[6] = (short)f2bf(b[2]); o[7] = (short)f2bf(b[3]);
    return o;
}

// ---------- dtype detection (single thread) — R1-proven ----------
__global__ void detect_kernel(const unsigned int* __restrict__ xw,
                              const unsigned int* __restrict__ eiw,
                              int* __restrict__ flags) {
    if (threadIdx.x == 0 && blockIdx.x == 0) {
        // bf16 N(0,1): exp field of low half-word in [100,130]; fp32: uniform mantissa bits
        int outliers = 0;
        for (int i = 0; i < 128; ++i) {
            unsigned int w = xw[i];
            int e = (int)((w >> 7) & 0xFFu);
            if (e < 100 || e > 130) outliers++;
        }
        flags[0] = (outliers < 16) ? 1 : 0;
        int zeros = 0;
        for (int i = 0; i < 64; ++i)
            if (eiw[2 * i + 1] == 0u) zeros++;
        flags[1] = (zeros >= 48) ? 1 : 0;
    }
}

__global__ void zero_int_kernel(int* __restrict__ p, int n) {
    int i = blockIdx.x * blockDim.x + threadIdx.x;
    if (i < n) p[i] = 0;
}

__global__ void hist_kernel(const void* __restrict__ ei, int E, int* __restrict__ deg,
                            const int* __restrict__ flags) {
    int e = blockIdx.x * blockDim.x + threadIdx.x;
    int i64f = flags[1];
    if (e < E) {
        int c = lde(ei, E + e, i64f);
        c = min(max(c, 0), NN - 1);
        atomicAdd(&deg[c], 1);
    }
}

__global__ void dinv_kernel(const int* __restrict__ deg, float* __restrict__ dinv, int n) {
    int i = blockIdx.x * blockDim.x + threadIdx.x;
    if (i < n) dinv[i] = rsqrtf((float)(deg[i] + 1));
}

// single-block scan — R1-proven
__global__ void scan_kernel(const int* __restrict__ deg, int* __restrict__ off,
                            int* __restrict__ cur, int n) {
    __shared__ int s[256];
    int tid = threadIdx.x;
    int carry = 0;
    for (int base = 0; base < n; base += 1024) {
        int idx = base + tid * 4;
        int v0 = (idx + 0 < n) ? deg[idx + 0] : 0;
        int v1 = (idx + 1 < n) ? deg[idx + 1] : 0;
        int v2 = (idx + 2 < n) ? deg[idx + 2] : 0;
        int v3 = (idx + 3 < n) ? deg[idx + 3] : 0;
        int tsum = v0 + v1 + v2 + v3;
        s[tid] = tsum;
        __syncthreads();
        for (int o = 1; o < 256; o <<= 1) {
            int t = (tid >= o) ? s[tid - o] : 0;
            __syncthreads();
            s[tid] += t;
            __syncthreads();
        }
        int excl = s[tid] - tsum;
        int total = s[255];
        int p = carry + excl;
        if (idx + 0 < n) { off[idx + 0] = p; cur[idx + 0] = p; } p += v0;
        if (idx + 1 < n) { off[idx + 1] = p; cur[idx + 1] = p; } p += v1;
        if (idx + 2 < n) { off[idx + 2] = p; cur[idx + 2] = p; } p += v2;
        if (idx + 3 < n) { off[idx + 3] = p; cur[idx + 3] = p; } p += v3;
        carry += total;
        __syncthreads();
    }
    if (tid == 0) off[n] = carry;
}

__global__ void scatter_kernel(const void* __restrict__ ei, const float* __restrict__ dinv,
                               int* __restrict__ cur, int* __restrict__ esrc,
                               float* __restrict__ ew, int E, const int* __restrict__ flags) {
    int e = blockIdx.x * blockDim.x + threadIdx.x;
    int i64f = flags[1];
    if (e < E) {
        int r = lde(ei, e, i64f);
        int c = lde(ei, E + e, i64f);
        r = min(max(r, 0), NN - 1);
        c = min(max(c, 0), NN - 1);
        int pos = atomicAdd(&cur[c], 1);
        esrc[pos] = r;
        ew[pos] = dinv[r] * dinv[c];
    }
}

// ---------- transpose+convert weights -> bf16: w1t[128][256], w2t[64][128] ----------
__global__ void transpose_w_kernel(const void* __restrict__ w1, const void* __restrict__ w2,
                                   unsigned short* __restrict__ w1t,
                                   unsigned short* __restrict__ w2t,
                                   const int* __restrict__ flags) {
    int bf = flags[0];
    int i = blockIdx.x * blockDim.x + threadIdx.x;
    if (i < 128 * 256) {
        int n = i >> 8, k = i & 255;
        float v = ldf(w1, k * 128 + n, bf);
        w1t[n * 256 + k] = f2bf(v);
    } else if (i < 128 * 256 + 64 * 128) {
        int j = i - 128 * 256;
        int n = j >> 7, k = j & 127;
        float v = ldf(w2, k * 64 + n, bf);
        w2t[n * 128 + k] = f2bf(v);
    }
}

// ---------- GEMM1 (MFMA): h1[N,128](bf16) = X[N,256] @ W1, fp32 accum ----------
// LDS: half of W1T at a time, padded rows (128+8 shorts) to spread banks.
__global__ __launch_bounds__(256) void gemm1_kernel(const void* __restrict__ x,
                                                    const unsigned short* __restrict__ wt,
                                                    unsigned short* __restrict__ h,
                                                    const int* __restrict__ flags) {
    __shared__ unsigned short wl[128 * 136];  // ~34 KB
    int bf = flags[0];
    int tid = threadIdx.x;
    int lane = tid & 63, wv = tid >> 6;
    int ln = lane & 15, kq = lane >> 4;
    int rowBase = blockIdx.x * 64 + wv * 16;
    int anode = min(rowBase + ln, NN - 1);
    size_t abase = (size_t)anode * 256;
    f32x4 acc[8];
#pragma unroll
    for (int t = 0; t < 8; ++t) acc[t] = (f32x4)0.f;

    for (int half = 0; half < 2; ++half) {
        __syncthreads();
        for (int i = tid; i < 128 * 16; i += 256) {
            int n = i >> 4, b = i & 15;
            short8 v = *(const short8*)(wt + n * 256 + half * 128 + b * 8);
            *(short8*)(&wl[n * 136 + b * 8]) = v;
        }
        __syncthreads();
#pragma unroll
        for (int ks = 0; ks < 4; ++ks) {
            int klocal = ks * 32 + kq * 8;
            short8 a = ld8bf(x, abase + half * 128 + klocal, bf);
#pragma unroll
            for (int t = 0; t < 8; ++t) {
                int n = t * 16 + ln;
                short8 b = *(const short8*)(&wl[n * 136 + klocal]);
                acc[t] = __builtin_amdgcn_mfma_f32_16x16x32_bf16(a, b, acc[t], 0, 0, 0);
            }
        }
    }
#pragma unroll
    for (int r = 0; r < 4; ++r) {
        int node = rowBase + kq * 4 + r;
        if (node < NN) {
            unsigned short* orow = h + (size_t)node * 128;
#pragma unroll
            for (int t = 0; t < 8; ++t)
                orow[t * 16 + ln] = f2bf(acc[t][r]);
        }
    }
}

// ---------- agg layer1: agg1[c] = relu(b1 + h[c]*dc^2 + sum h[src]*w), bf16 ----------
__global__ __launch_bounds__(256) void agg1_kernel(const unsigned short* __restrict__ h,
                                                   const float* __restrict__ dinv,
                                                   const int* __restrict__ off,
                                                   const int* __restrict__ esrc,
                                                   const float* __restrict__ ew,
                                                   const void* __restrict__ b1,
                                                   unsigned short* __restrict__ outp,
                                                   const int* __restrict__ flags) {
    int lane = threadIdx.x & 63;
    int c = blockIdx.x * 4 + (threadIdx.x >> 6);
    if (c >= NN) return;
    int bf = flags[0];
    int g = lane >> 4, l = lane & 15;  // 4 edge-groups x 16 feature-lanes (8 feats each)
    float acc[8];
    float dc = dinv[c];
    if (g == 0) {
        short8 v = *(const short8*)(h + (size_t)c * 128 + l * 8);
        float w = dc * dc;
#pragma unroll
        for (int f = 0; f < 8; ++f) acc[f] = bf2f((unsigned short)v[f]) * w;
    } else {
#pragma unroll
        for (int f = 0; f < 8; ++f) acc[f] = 0.f;
    }
    int e = off[c + 1];
    for (int j = off[c] + g; j < e; j += 4) {
        int src = min(max(esrc[j], 0), NN - 1);  // insurance vs poison
        float w = ew[j];
        short8 v = *(const short8*)(h + (size_t)src * 128 + l * 8);
#pragma unroll
        for (int f = 0; f < 8; ++f) acc[f] = fmaf(bf2f((unsigned short)v[f]), w, acc[f]);
    }
#pragma unroll
    for (int f = 0; f < 8; ++f) {
        acc[f] += __shfl_xor(acc[f], 16, 64);
        acc[f] += __shfl_xor(acc[f], 32, 64);
    }
    if (g == 0) {
        short8 o;
#pragma unroll
        for (int f = 0; f < 8; ++f)
            o[f] = (short)f2bf(fmaxf(acc[f] + ldf(b1, l * 8 + f, bf), 0.f));
        *(short8*)(outp + (size_t)c * 128 + l * 8) = o;
    }
}

// ---------- GEMM2 (MFMA): h2[N,64](bf16) = agg1[N,128] @ W2 ----------
__global__ __launch_bounds__(256) void gemm2_kernel(const unsigned short* __restrict__ a_,
                                                    const unsigned short* __restrict__ wt,
                                                    unsigned short* __restrict__ h2) {
    __shared__ unsigned short wl[64 * 136];  // ~17 KB
    int tid = threadIdx.x;
    for (int i = tid; i < 64 * 16; i += 256) {
        int n = i >> 4, b = i & 15;
        short8 v = *(const short8*)(wt + n * 128 + b * 8);
        *(short8*)(&wl[n * 136 + b * 8]) = v;
    }
    __syncthreads();
    int lane = tid & 63, wv = tid >> 6;
    int ln = lane & 15, kq = lane >> 4;
    int rowBase = blockIdx.x * 64 + wv * 16;
    int anode = min(rowBase + ln, NN - 1);
    const unsigned short* arow = a_ + (size_t)anode * 128;
    f32x4 acc[4];
#pragma unroll
    for (int t = 0; t < 4; ++t) acc[t] = (f32x4)0.f;
#pragma unroll
    for (int ks = 0; ks < 4; ++ks) {
        int k0 = ks * 32 + kq * 8;
        short8 a = *(const short8*)(arow + k0);
#pragma unroll
        for (int t = 0; t < 4; ++t) {
            int n = t * 16 + ln;
            short8 b = *(const short8*)(&wl[n * 136 + k0]);
            acc[t] = __builtin_amdgcn_mfma_f32_16x16x32_bf16(a, b, acc[t], 0, 0, 0);
        }
    }
#pragma unroll
    for (int r = 0; r < 4; ++r) {
        int node = rowBase + kq * 4 + r;
        if (node < NN) {
            unsigned short* orow = h2 + (size_t)node * 64;
#pragma unroll
            for (int t = 0; t < 4; ++t)
                orow[t * 16 + ln] = f2bf(acc[t][r]);
        }
    }
}

// ---------- agg layer2 fused with +b2, flag-dtyped output ----------
__global__ __launch_bounds__(256) void agg_out_kernel(const unsigned short* __restrict__ h,
                                                      const float* __restrict__ dinv,
                                                      const int* __restrict__ off,
                                                      const int* __restrict__ esrc,
                                                      const float* __restrict__ ew,
                                                      const void* __restrict__ b2,
                                                      void* __restrict__ outp,
                                                      const int* __restrict__ flags) {
    int lane = threadIdx.x & 63;
    int c = blockIdx.x * 4 + (threadIdx.x >> 6);
    if (c >= NN) return;
    int bf = flags[0];
    int g = lane >> 3, l = lane & 7;  // 8 edge-groups x 8 feature-lanes (8 feats each)
    float acc[8];
    float dc = dinv[c];
    if (g == 0) {
        short8 v = *(const short8*)(h + (size_t)c * 64 + l * 8);
        float w = dc * dc;
#pragma unroll
        for (int f = 0; f < 8; ++f) acc[f] = bf2f((unsigned short)v[f]) * w;
    } else {
#pragma unroll
        for (int f = 0; f < 8; ++f) acc[f] = 0.f;
    }
    int e = off[c + 1];
    for (int j = off[c] + g; j < e; j += 8) {
        int src = min(max(esrc[j], 0), NN - 1);  // insurance vs poison
        float w = ew[j];
        short8 v = *(const short8*)(h + (size_t)src * 64 + l * 8);
#pragma unroll
        for (int f = 0; f < 8; ++f) acc[f] = fmaf(bf2f((unsigned short)v[f]), w, acc[f]);
    }
#pragma unroll
    for (int f = 0; f < 8; ++f) {
        acc[f] += __shfl_xor(acc[f], 8, 64);
        acc[f] += __shfl_xor(acc[f], 16, 64);
        acc[f] += __shfl_xor(acc[f], 32, 64);
    }
    if (g == 0) {
        if (bf) {
            short8 o;
#pragma unroll
            for (int f = 0; f < 8; ++f)
                o[f] = (short)f2bf(acc[f] + ldf(b2, l * 8 + f, 1));
            *(short8*)((unsigned short*)outp + (size_t)c * 64 + l * 8) = o;
        } else {
            float* op = (float*)outp + (size_t)c * 64 + l * 8;
#pragma unroll
            for (int f = 0; f < 8; ++f)
                op[f] = acc[f] + ldf(b2, l * 8 + f, 0);
        }
    }
}

extern "C" void kernel_launch(void* const* d_in, const int* in_sizes, int n_in,
                              void* d_out, int out_size, void* d_ws, size_t ws_size,
                              hipStream_t stream) {
    const void* x  = d_in[0];
    const void* ei = d_in[1];
    const void* W1 = d_in[2];
    const void* b1 = d_in[3];
    const void* W2 = d_in[4];
    const void* b2 = d_in[5];

    const int N = NN;
    const int E = in_sizes[1] / 2;

    char* ws = (char*)d_ws;
    size_t o = 0;
    auto alloc = [&](size_t bytes) { size_t r = o; o += (bytes + 255) & ~(size_t)255; return r; };
    int*   flags = (int*)(ws + alloc(256));
    int*   deg   = (int*)(ws + alloc((size_t)N * 4));
    float* dinv  = (float*)(ws + alloc((size_t)N * 4));
    int*   off   = (int*)(ws + alloc((size_t)(N + 1) * 4));
    int*   cur   = (int*)(ws + alloc((size_t)N * 4));
    int*   esrc  = (int*)(ws + alloc((size_t)E * 4));
    float* ew    = (float*)(ws + alloc((size_t)E * 4));
    unsigned short* w1t  = (unsigned short*)(ws + alloc(128 * 256 * 2));
    unsigned short* w2t  = (unsigned short*)(ws + alloc(64 * 128 * 2));
    unsigned short* h1   = (unsigned short*)(ws + alloc((size_t)N * 128 * 2));
    unsigned short* agg1 = (unsigned short*)(ws + alloc((size_t)N * 128 * 2));
    unsigned short* h2   = h1;  // reuse (h1 dead after agg1_kernel)

    detect_kernel<<<1, 1, 0, stream>>>((const unsigned int*)x, (const unsigned int*)ei, flags);
    zero_int_kernel<<<(N + 255) / 256, 256, 0, stream>>>(deg, N);
    hist_kernel<<<(E + 255) / 256, 256, 0, stream>>>(ei, E, deg, flags);
    dinv_kernel<<<(N + 255) / 256, 256, 0, stream>>>(deg, dinv, N);
    scan_kernel<<<1, 256, 0, stream>>>(deg, off, cur, N);
    scatter_kernel<<<(E + 255) / 256, 256, 0, stream>>>(ei, dinv, cur, esrc, ew, E, flags);
    transpose_w_kernel<<<(128 * 256 + 64 * 128 + 255) / 256, 256, 0, stream>>>(W1, W2, w1t, w2t, flags);

    gemm1_kernel<<<(N + 63) / 64, 256, 0, stream>>>(x, w1t, h1, flags);
    agg1_kernel<<<(N + 3) / 4, 256, 0, stream>>>(h1, dinv, off, esrc, ew, b1, agg1, flags);
    gemm2_kernel<<<(N + 63) / 64, 256, 0, stream>>>(agg1, w2t, h2);
    agg_out_kernel<<<(N + 3) / 4, 256, 0, stream>>>(h2, dinv, off, esrc, ew, b2, d_out, flags);
}

// Round 5
// 510.160 us; speedup vs baseline: 2.2104x; 1.3007x over previous
//
#include <hip/hip_runtime.h>

#define NN 100000

typedef __attribute__((ext_vector_type(8))) short short8;
typedef __attribute__((ext_vector_type(4))) float f32x4;

// ---------- bf16 helpers ----------
__device__ __forceinline__ float bf2f(unsigned short u) {
    union { unsigned int i; float f; } v;
    v.i = ((unsigned int)u) << 16;
    return v.f;
}
__device__ __forceinline__ unsigned short f2bf(float f) {
    unsigned int u = __float_as_uint(f);
    unsigned int r = u + 0x7fffu + ((u >> 16) & 1u);  // RNE
    return (unsigned short)(r >> 16);
}
// flags[0]=1 -> float tensors are bf16, else fp32
__device__ __forceinline__ float ldf(const void* p, int i, int bf) {
    return bf ? bf2f(((const unsigned short*)p)[i]) : ((const float*)p)[i];
}
// flags[1]=1 -> edge_index is int64, else int32
__device__ __forceinline__ int lde(const void* p, int i, int i64f) {
    return i64f ? (int)((const long long*)p)[i] : ((const int*)p)[i];
}
// load 8 consecutive float-typed input elements as bf16 short8 (flag-driven)
__device__ __forceinline__ short8 ld8bf(const void* p, size_t i, int bf) {
    if (bf) return *(const short8*)((const unsigned short*)p + i);
    const float* f = (const float*)p + i;
    f32x4 a = *(const f32x4*)f;
    f32x4 b = *(const f32x4*)(f + 4);
    short8 o;
    o[0] = (short)f2bf(a[0]); o[1] = (short)f2bf(a[1]);
    o[2] = (short)f2bf(a[2]); o[3] = (short)f2bf(a[3]);
    o[4] = (short)f2bf(b[0]); o[5] = (short)f2bf(b[1]);
    o[6] = (short)f2bf(b[2]); o[7] = (short)f2bf(b[3]);
    return o;
}

// ---------- dtype detection (single thread) — proven ----------
__global__ void detect_kernel(const unsigned int* __restrict__ xw,
                              const unsigned int* __restrict__ eiw,
                              int* __restrict__ flags) {
    if (threadIdx.x == 0 && blockIdx.x == 0) {
        int outliers = 0;
        for (int i = 0; i < 128; ++i) {
            unsigned int w = xw[i];
            int e = (int)((w >> 7) & 0xFFu);
            if (e < 100 || e > 130) outliers++;
        }
        flags[0] = (outliers < 16) ? 1 : 0;
        int zeros = 0;
        for (int i = 0; i < 64; ++i)
            if (eiw[2 * i + 1] == 0u) zeros++;
        flags[1] = (zeros >= 48) ? 1 : 0;
    }
}

__global__ void zero_int_kernel(int* __restrict__ p, int n) {
    int i = blockIdx.x * blockDim.x + threadIdx.x;
    if (i < n) p[i] = 0;
}

__global__ void hist_kernel(const void* __restrict__ ei, int E, int* __restrict__ deg,
                            const int* __restrict__ flags) {
    int e = blockIdx.x * blockDim.x + threadIdx.x;
    int i64f = flags[1];
    if (e < E) {
        int c = lde(ei, E + e, i64f);
        c = min(max(c, 0), NN - 1);
        atomicAdd(&deg[c], 1);
    }
}

__global__ void dinv_kernel(const int* __restrict__ deg, float* __restrict__ dinv, int n) {
    int i = blockIdx.x * blockDim.x + threadIdx.x;
    if (i < n) dinv[i] = rsqrtf((float)(deg[i] + 1));
}

// ---------- parallel scan: 98 chunks of 1024 ----------
__global__ void scan_part_kernel(const int* __restrict__ deg, int* __restrict__ psum, int n) {
    __shared__ int s[256];
    int tid = threadIdx.x;
    int base = blockIdx.x * 1024 + tid * 4;
    int t = 0;
#pragma unroll
    for (int q = 0; q < 4; ++q) t += (base + q < n) ? deg[base + q] : 0;
    s[tid] = t;
    __syncthreads();
    for (int o = 128; o > 0; o >>= 1) {
        if (tid < o) s[tid] += s[tid + o];
        __syncthreads();
    }
    if (tid == 0) psum[blockIdx.x] = s[0];
}

__global__ void scan_top_kernel(int* __restrict__ psum, int nchunks, int* __restrict__ off, int n) {
    if (threadIdx.x == 0) {
        int acc = 0;
        for (int i = 0; i < nchunks; ++i) {
            int v = psum[i];
            psum[i] = acc;
            acc += v;
        }
        off[n] = acc;
    }
}

__global__ void scan_final_kernel(const int* __restrict__ deg, const int* __restrict__ psum,
                                  int* __restrict__ off, int* __restrict__ cur, int n) {
    __shared__ int s[256];
    int tid = threadIdx.x;
    int idx = blockIdx.x * 1024 + tid * 4;
    int v0 = (idx + 0 < n) ? deg[idx + 0] : 0;
    int v1 = (idx + 1 < n) ? deg[idx + 1] : 0;
    int v2 = (idx + 2 < n) ? deg[idx + 2] : 0;
    int v3 = (idx + 3 < n) ? deg[idx + 3] : 0;
    int tsum = v0 + v1 + v2 + v3;
    s[tid] = tsum;
    __syncthreads();
    for (int o = 1; o < 256; o <<= 1) {
        int t = (tid >= o) ? s[tid - o] : 0;
        __syncthreads();
        s[tid] += t;
        __syncthreads();
    }
    int p = psum[blockIdx.x] + s[tid] - tsum;
    if (idx + 0 < n) { off[idx + 0] = p; cur[idx + 0] = p; } p += v0;
    if (idx + 1 < n) { off[idx + 1] = p; cur[idx + 1] = p; } p += v1;
    if (idx + 2 < n) { off[idx + 2] = p; cur[idx + 2] = p; } p += v2;
    if (idx + 3 < n) { off[idx + 3] = p; cur[idx + 3] = p; }
}

__global__ void scatter_kernel(const void* __restrict__ ei, const float* __restrict__ dinv,
                               int* __restrict__ cur, int* __restrict__ esrc,
                               float* __restrict__ ew, int E, const int* __restrict__ flags) {
    int e = blockIdx.x * blockDim.x + threadIdx.x;
    int i64f = flags[1];
    if (e < E) {
        int r = lde(ei, e, i64f);
        int c = lde(ei, E + e, i64f);
        r = min(max(r, 0), NN - 1);
        c = min(max(c, 0), NN - 1);
        int pos = atomicAdd(&cur[c], 1);
        esrc[pos] = r;
        ew[pos] = dinv[r] * dinv[c];
    }
}

// ---------- transpose+convert weights -> bf16: w1t[128][256], w2t[64][128] ----------
__global__ void transpose_w_kernel(const void* __restrict__ w1, const void* __restrict__ w2,
                                   unsigned short* __restrict__ w1t,
                                   unsigned short* __restrict__ w2t,
                                   const int* __restrict__ flags) {
    int bf = flags[0];
    int i = blockIdx.x * blockDim.x + threadIdx.x;
    if (i < 128 * 256) {
        int n = i >> 8, k = i & 255;
        float v = ldf(w1, k * 128 + n, bf);
        w1t[n * 256 + k] = f2bf(v);
    } else if (i < 128 * 256 + 64 * 128) {
        int j = i - 128 * 256;
        int n = j >> 7, k = j & 127;
        float v = ldf(w2, k * 64 + n, bf);
        w2t[n * 128 + k] = f2bf(v);
    }
}

// ---------- GEMM1 (MFMA): h1[N,128](bf16) = X[N,256] @ W1, fp32 accum ----------
__global__ __launch_bounds__(256) void gemm1_kernel(const void* __restrict__ x,
                                                    const unsigned short* __restrict__ wt,
                                                    unsigned short* __restrict__ h,
                                                    const int* __restrict__ flags) {
    __shared__ unsigned short wl[128 * 136];  // ~34 KB
    int bf = flags[0];
    int tid = threadIdx.x;
    int lane = tid & 63, wv = tid >> 6;
    int ln = lane & 15, kq = lane >> 4;
    int rowBase = blockIdx.x * 64 + wv * 16;
    int anode = min(rowBase + ln, NN - 1);
    size_t abase = (size_t)anode * 256;
    f32x4 acc[8];
#pragma unroll
    for (int t = 0; t < 8; ++t) acc[t] = (f32x4)0.f;

    for (int half = 0; half < 2; ++half) {
        __syncthreads();
        for (int i = tid; i < 128 * 16; i += 256) {
            int n = i >> 4, b = i & 15;
            short8 v = *(const short8*)(wt + n * 256 + half * 128 + b * 8);
            *(short8*)(&wl[n * 136 + b * 8]) = v;
        }
        __syncthreads();
#pragma unroll
        for (int ks = 0; ks < 4; ++ks) {
            int klocal = ks * 32 + kq * 8;
            short8 a = ld8bf(x, abase + half * 128 + klocal, bf);
#pragma unroll
            for (int t = 0; t < 8; ++t) {
                int n = t * 16 + ln;
                short8 b = *(const short8*)(&wl[n * 136 + klocal]);
                acc[t] = __builtin_amdgcn_mfma_f32_16x16x32_bf16(a, b, acc[t], 0, 0, 0);
            }
        }
    }
#pragma unroll
    for (int r = 0; r < 4; ++r) {
        int node = rowBase + kq * 4 + r;
        if (node < NN) {
            unsigned short* orow = h + (size_t)node * 128;
#pragma unroll
            for (int t = 0; t < 8; ++t)
                orow[t * 16 + ln] = f2bf(acc[t][r]);
        }
    }
}

// ---------- agg layer1: agg1[c] = relu(b1 + h[c]*dc^2 + sum h[src]*w), bf16 ----------
__global__ __launch_bounds__(256) void agg1_kernel(const unsigned short* __restrict__ h,
                                                   const float* __restrict__ dinv,
                                                   const int* __restrict__ off,
                                                   const int* __restrict__ esrc,
                                                   const float* __restrict__ ew,
                                                   const void* __restrict__ b1,
                                                   unsigned short* __restrict__ outp,
                                                   const int* __restrict__ flags) {
    int lane = threadIdx.x & 63;
    int c = blockIdx.x * 4 + (threadIdx.x >> 6);
    if (c >= NN) return;
    int bf = flags[0];
    int g = lane >> 4, l = lane & 15;  // 4 edge-groups x 16 feature-lanes (8 feats each)
    float acc[8];
    float dc = dinv[c];
    if (g == 0) {
        short8 v = *(const short8*)(h + (size_t)c * 128 + l * 8);
        float w = dc * dc;
#pragma unroll
        for (int f = 0; f < 8; ++f) acc[f] = bf2f((unsigned short)v[f]) * w;
    } else {
#pragma unroll
        for (int f = 0; f < 8; ++f) acc[f] = 0.f;
    }
    int e = off[c + 1];
    for (int j = off[c] + g; j < e; j += 4) {
        int src = min(max(esrc[j], 0), NN - 1);
        float w = ew[j];
        short8 v = *(const short8*)(h + (size_t)src * 128 + l * 8);
#pragma unroll
        for (int f = 0; f < 8; ++f) acc[f] = fmaf(bf2f((unsigned short)v[f]), w, acc[f]);
    }
#pragma unroll
    for (int f = 0; f < 8; ++f) {
        acc[f] += __shfl_xor(acc[f], 16, 64);
        acc[f] += __shfl_xor(acc[f], 32, 64);
    }
    if (g == 0) {
        short8 o;
#pragma unroll
        for (int f = 0; f < 8; ++f)
            o[f] = (short)f2bf(fmaxf(acc[f] + ldf(b1, l * 8 + f, bf), 0.f));
        *(short8*)(outp + (size_t)c * 128 + l * 8) = o;
    }
}

// ---------- GEMM2 (MFMA): h2[N,64](bf16) = agg1[N,128] @ W2 ----------
__global__ __launch_bounds__(256) void gemm2_kernel(const unsigned short* __restrict__ a_,
                                                    const unsigned short* __restrict__ wt,
                                                    unsigned short* __restrict__ h2) {
    __shared__ unsigned short wl[64 * 136];  // ~17 KB
    int tid = threadIdx.x;
    for (int i = tid; i < 64 * 16; i += 256) {
        int n = i >> 4, b = i & 15;
        short8 v = *(const short8*)(wt + n * 128 + b * 8);
        *(short8*)(&wl[n * 136 + b * 8]) = v;
    }
    __syncthreads();
    int lane = tid & 63, wv = tid >> 6;
    int ln = lane & 15, kq = lane >> 4;
    int rowBase = blockIdx.x * 64 + wv * 16;
    int anode = min(rowBase + ln, NN - 1);
    const unsigned short* arow = a_ + (size_t)anode * 128;
    f32x4 acc[4];
#pragma unroll
    for (int t = 0; t < 4; ++t) acc[t] = (f32x4)0.f;
#pragma unroll
    for (int ks = 0; ks < 4; ++ks) {
        int k0 = ks * 32 + kq * 8;
        short8 a = *(const short8*)(arow + k0);
#pragma unroll
        for (int t = 0; t < 4; ++t) {
            int n = t * 16 + ln;
            short8 b = *(const short8*)(&wl[n * 136 + k0]);
            acc[t] = __builtin_amdgcn_mfma_f32_16x16x32_bf16(a, b, acc[t], 0, 0, 0);
        }
    }
#pragma unroll
    for (int r = 0; r < 4; ++r) {
        int node = rowBase + kq * 4 + r;
        if (node < NN) {
            unsigned short* orow = h2 + (size_t)node * 64;
#pragma unroll
            for (int t = 0; t < 4; ++t)
                orow[t * 16 + ln] = f2bf(acc[t][r]);
        }
    }
}

// ---------- agg layer2 fused with +b2, flag-dtyped output ----------
__global__ __launch_bounds__(256) void agg_out_kernel(const unsigned short* __restrict__ h,
                                                      const float* __restrict__ dinv,
                                                      const int* __restrict__ off,
                                                      const int* __restrict__ esrc,
                                                      const float* __restrict__ ew,
                                                      const void* __restrict__ b2,
                                                      void* __restrict__ outp,
                                                      const int* __restrict__ flags) {
    int lane = threadIdx.x & 63;
    int c = blockIdx.x * 4 + (threadIdx.x >> 6);
    if (c >= NN) return;
    int bf = flags[0];
    int g = lane >> 3, l = lane & 7;  // 8 edge-groups x 8 feature-lanes (8 feats each)
    float acc[8];
    float dc = dinv[c];
    if (g == 0) {
        short8 v = *(const short8*)(h + (size_t)c * 64 + l * 8);
        float w = dc * dc;
#pragma unroll
        for (int f = 0; f < 8; ++f) acc[f] = bf2f((unsigned short)v[f]) * w;
    } else {
#pragma unroll
        for (int f = 0; f < 8; ++f) acc[f] = 0.f;
    }
    int e = off[c + 1];
    for (int j = off[c] + g; j < e; j += 8) {
        int src = min(max(esrc[j], 0), NN - 1);
        float w = ew[j];
        short8 v = *(const short8*)(h + (size_t)src * 64 + l * 8);
#pragma unroll
        for (int f = 0; f < 8; ++f) acc[f] = fmaf(bf2f((unsigned short)v[f]), w, acc[f]);
    }
#pragma unroll
    for (int f = 0; f < 8; ++f) {
        acc[f] += __shfl_xor(acc[f], 8, 64);
        acc[f] += __shfl_xor(acc[f], 16, 64);
        acc[f] += __shfl_xor(acc[f], 32, 64);
    }
    if (g == 0) {
        if (bf) {
            short8 o;
#pragma unroll
            for (int f = 0; f < 8; ++f)
                o[f] = (short)f2bf(acc[f] + ldf(b2, l * 8 + f, 1));
            *(short8*)((unsigned short*)outp + (size_t)c * 64 + l * 8) = o;
        } else {
            float* op = (float*)outp + (size_t)c * 64 + l * 8;
#pragma unroll
            for (int f = 0; f < 8; ++f)
                op[f] = acc[f] + ldf(b2, l * 8 + f, 0);
        }
    }
}

extern "C" void kernel_launch(void* const* d_in, const int* in_sizes, int n_in,
                              void* d_out, int out_size, void* d_ws, size_t ws_size,
                              hipStream_t stream) {
    const void* x  = d_in[0];
    const void* ei = d_in[1];
    const void* W1 = d_in[2];
    const void* b1 = d_in[3];
    const void* W2 = d_in[4];
    const void* b2 = d_in[5];

    const int N = NN;
    const int E = in_sizes[1] / 2;
    const int NCHUNK = (N + 1023) / 1024;

    char* ws = (char*)d_ws;
    size_t o = 0;
    auto alloc = [&](size_t bytes) { size_t r = o; o += (bytes + 255) & ~(size_t)255; return r; };
    int*   flags = (int*)(ws + alloc(256));
    int*   deg   = (int*)(ws + alloc((size_t)N * 4));
    float* dinv  = (float*)(ws + alloc((size_t)N * 4));
    int*   off   = (int*)(ws + alloc((size_t)(N + 1) * 4));
    int*   cur   = (int*)(ws + alloc((size_t)N * 4));
    int*   psum  = (int*)(ws + alloc((size_t)NCHUNK * 4));
    int*   esrc  = (int*)(ws + alloc((size_t)E * 4));
    float* ew    = (float*)(ws + alloc((size_t)E * 4));
    unsigned short* w1t  = (unsigned short*)(ws + alloc(128 * 256 * 2));
    unsigned short* w2t  = (unsigned short*)(ws + alloc(64 * 128 * 2));
    unsigned short* h1   = (unsigned short*)(ws + alloc((size_t)N * 128 * 2));
    unsigned short* agg1 = (unsigned short*)(ws + alloc((size_t)N * 128 * 2));
    unsigned short* h2   = h1;  // reuse (h1 dead after agg1_kernel)

    detect_kernel<<<1, 1, 0, stream>>>((const unsigned int*)x, (const unsigned int*)ei, flags);
    zero_int_kernel<<<(N + 255) / 256, 256, 0, stream>>>(deg, N);
    hist_kernel<<<(E + 255) / 256, 256, 0, stream>>>(ei, E, deg, flags);
    dinv_kernel<<<(N + 255) / 256, 256, 0, stream>>>(deg, dinv, N);
    scan_part_kernel<<<NCHUNK, 256, 0, stream>>>(deg, psum, N);
    scan_top_kernel<<<1, 1, 0, stream>>>(psum, NCHUNK, off, N);
    scan_final_kernel<<<NCHUNK, 256, 0, stream>>>(deg, psum, off, cur, N);
    scatter_kernel<<<(E + 255) / 256, 256, 0, stream>>>(ei, dinv, cur, esrc, ew, E, flags);
    transpose_w_kernel<<<(128 * 256 + 64 * 128 + 255) / 256, 256, 0, stream>>>(W1, W2, w1t, w2t, flags);

    gemm1_kernel<<<(N + 63) / 64, 256, 0, stream>>>(x, w1t, h1, flags);
    agg1_kernel<<<(N + 3) / 4, 256, 0, stream>>>(h1, dinv, off, esrc, ew, b1, agg1, flags);
    gemm2_kernel<<<(N + 63) / 64, 256, 0, stream>>>(agg1, w2t, h2);
    agg_out_kernel<<<(N + 3) / 4, 256, 0, stream>>>(h2, dinv, off, esrc, ew, b2, d_out, flags);
}

// Round 6
// 492.899 us; speedup vs baseline: 2.2878x; 1.0350x over previous
//
#include <hip/hip_runtime.h>

#define NN 100000

typedef __attribute__((ext_vector_type(8))) short short8;
typedef __attribute__((ext_vector_type(4))) float f32x4;

// ---------- bf16 helpers ----------
__device__ __forceinline__ float bf2f(unsigned short u) {
    union { unsigned int i; float f; } v;
    v.i = ((unsigned int)u) << 16;
    return v.f;
}
__device__ __forceinline__ unsigned short f2bf(float f) {
    unsigned int u = __float_as_uint(f);
    unsigned int r = u + 0x7fffu + ((u >> 16) & 1u);  // RNE
    return (unsigned short)(r >> 16);
}
// flags[0]=1 -> float tensors are bf16, else fp32
__device__ __forceinline__ float ldf(const void* p, int i, int bf) {
    return bf ? bf2f(((const unsigned short*)p)[i]) : ((const float*)p)[i];
}
// flags[1]=1 -> edge_index is int64, else int32
__device__ __forceinline__ int lde(const void* p, int i, int i64f) {
    return i64f ? (int)((const long long*)p)[i] : ((const int*)p)[i];
}
// load 8 consecutive float-typed input elements as bf16 short8 (flag-driven)
__device__ __forceinline__ short8 ld8bf(const void* p, size_t i, int bf) {
    if (bf) return *(const short8*)((const unsigned short*)p + i);
    const float* f = (const float*)p + i;
    f32x4 a = *(const f32x4*)f;
    f32x4 b = *(const f32x4*)(f + 4);
    short8 o;
    o[0] = (short)f2bf(a[0]); o[1] = (short)f2bf(a[1]);
    o[2] = (short)f2bf(a[2]); o[3] = (short)f2bf(a[3]);
    o[4] = (short)f2bf(b[0]); o[5] = (short)f2bf(b[1]);
    o[6] = (short)f2bf(b[2]); o[7] = (short)f2bf(b[3]);
    return o;
}

// ---------- dtype detection (single thread) — proven ----------
__global__ void detect_kernel(const unsigned int* __restrict__ xw,
                              const unsigned int* __restrict__ eiw,
                              int* __restrict__ flags) {
    if (threadIdx.x == 0 && blockIdx.x == 0) {
        int outliers = 0;
        for (int i = 0; i < 128; ++i) {
            unsigned int w = xw[i];
            int e = (int)((w >> 7) & 0xFFu);
            if (e < 100 || e > 130) outliers++;
        }
        flags[0] = (outliers < 16) ? 1 : 0;
        int zeros = 0;
        for (int i = 0; i < 64; ++i)
            if (eiw[2 * i + 1] == 0u) zeros++;
        flags[1] = (zeros >= 48) ? 1 : 0;
    }
}

__global__ void zero_int_kernel(int* __restrict__ p, int n) {
    int i = blockIdx.x * blockDim.x + threadIdx.x;
    if (i < n) p[i] = 0;
}

__global__ void hist_kernel(const void* __restrict__ ei, int E, int* __restrict__ deg,
                            const int* __restrict__ flags) {
    int e = blockIdx.x * blockDim.x + threadIdx.x;
    int i64f = flags[1];
    if (e < E) {
        int c = lde(ei, E + e, i64f);
        c = min(max(c, 0), NN - 1);
        atomicAdd(&deg[c], 1);
    }
}

// ---------- parallel scan: 98 chunks of 1024 (dinv fused in) ----------
__global__ void scan_part_kernel(const int* __restrict__ deg, int* __restrict__ psum,
                                 float* __restrict__ dinv, int n) {
    __shared__ int s[256];
    int tid = threadIdx.x;
    int base = blockIdx.x * 1024 + tid * 4;
    int t = 0;
#pragma unroll
    for (int q = 0; q < 4; ++q) {
        if (base + q < n) {
            int d = deg[base + q];
            t += d;
            dinv[base + q] = rsqrtf((float)(d + 1));
        }
    }
    s[tid] = t;
    __syncthreads();
    for (int o = 128; o > 0; o >>= 1) {
        if (tid < o) s[tid] += s[tid + o];
        __syncthreads();
    }
    if (tid == 0) psum[blockIdx.x] = s[0];
}

__global__ void scan_top_kernel(int* __restrict__ psum, int nchunks, int* __restrict__ off, int n) {
    if (threadIdx.x == 0) {
        int acc = 0;
        for (int i = 0; i < nchunks; ++i) {
            int v = psum[i];
            psum[i] = acc;
            acc += v;
        }
        off[n] = acc;
    }
}

__global__ void scan_final_kernel(const int* __restrict__ deg, const int* __restrict__ psum,
                                  int* __restrict__ off, int* __restrict__ cur, int n) {
    __shared__ int s[256];
    int tid = threadIdx.x;
    int idx = blockIdx.x * 1024 + tid * 4;
    int v0 = (idx + 0 < n) ? deg[idx + 0] : 0;
    int v1 = (idx + 1 < n) ? deg[idx + 1] : 0;
    int v2 = (idx + 2 < n) ? deg[idx + 2] : 0;
    int v3 = (idx + 3 < n) ? deg[idx + 3] : 0;
    int tsum = v0 + v1 + v2 + v3;
    s[tid] = tsum;
    __syncthreads();
    for (int o = 1; o < 256; o <<= 1) {
        int t = (tid >= o) ? s[tid - o] : 0;
        __syncthreads();
        s[tid] += t;
        __syncthreads();
    }
    int p = psum[blockIdx.x] + s[tid] - tsum;
    if (idx + 0 < n) { off[idx + 0] = p; cur[idx + 0] = p; } p += v0;
    if (idx + 1 < n) { off[idx + 1] = p; cur[idx + 1] = p; } p += v1;
    if (idx + 2 < n) { off[idx + 2] = p; cur[idx + 2] = p; } p += v2;
    if (idx + 3 < n) { off[idx + 3] = p; cur[idx + 3] = p; }
}

// ---------- CSR scatter: ONE 8B store per edge (src, weight) ----------
__global__ void scatter_kernel(const void* __restrict__ ei, const float* __restrict__ dinv,
                               int* __restrict__ cur, int2* __restrict__ epair,
                               int E, const int* __restrict__ flags) {
    int e = blockIdx.x * blockDim.x + threadIdx.x;
    int i64f = flags[1];
    if (e < E) {
        int r = lde(ei, e, i64f);
        int c = lde(ei, E + e, i64f);
        r = min(max(r, 0), NN - 1);
        c = min(max(c, 0), NN - 1);
        int pos = atomicAdd(&cur[c], 1);
        epair[pos] = make_int2(r, __float_as_int(dinv[r] * dinv[c]));
    }
}

// ---------- transpose+convert weights -> bf16: w1t[128][256], w2t[64][128] ----------
__global__ void transpose_w_kernel(const void* __restrict__ w1, const void* __restrict__ w2,
                                   unsigned short* __restrict__ w1t,
                                   unsigned short* __restrict__ w2t,
                                   const int* __restrict__ flags) {
    int bf = flags[0];
    int i = blockIdx.x * blockDim.x + threadIdx.x;
    if (i < 128 * 256) {
        int n = i >> 8, k = i & 255;
        float v = ldf(w1, k * 128 + n, bf);
        w1t[n * 256 + k] = f2bf(v);
    } else if (i < 128 * 256 + 64 * 128) {
        int j = i - 128 * 256;
        int n = j >> 7, k = j & 127;
        float v = ldf(w2, k * 64 + n, bf);
        w2t[n * 128 + k] = f2bf(v);
    }
}

// ---------- GEMM1 (MFMA): h1[N,128](bf16) = X[N,256] @ W1, fp32 accum ----------
__global__ __launch_bounds__(256) void gemm1_kernel(const void* __restrict__ x,
                                                    const unsigned short* __restrict__ wt,
                                                    unsigned short* __restrict__ h,
                                                    const int* __restrict__ flags) {
    __shared__ unsigned short wl[128 * 136];  // ~34 KB
    int bf = flags[0];
    int tid = threadIdx.x;
    int lane = tid & 63, wv = tid >> 6;
    int ln = lane & 15, kq = lane >> 4;
    int rowBase = blockIdx.x * 64 + wv * 16;
    int anode = min(rowBase + ln, NN - 1);
    size_t abase = (size_t)anode * 256;
    f32x4 acc[8];
#pragma unroll
    for (int t = 0; t < 8; ++t) acc[t] = (f32x4)0.f;

    for (int half = 0; half < 2; ++half) {
        __syncthreads();
        for (int i = tid; i < 128 * 16; i += 256) {
            int n = i >> 4, b = i & 15;
            short8 v = *(const short8*)(wt + n * 256 + half * 128 + b * 8);
            *(short8*)(&wl[n * 136 + b * 8]) = v;
        }
        __syncthreads();
#pragma unroll
        for (int ks = 0; ks < 4; ++ks) {
            int klocal = ks * 32 + kq * 8;
            short8 a = ld8bf(x, abase + half * 128 + klocal, bf);
#pragma unroll
            for (int t = 0; t < 8; ++t) {
                int n = t * 16 + ln;
                short8 b = *(const short8*)(&wl[n * 136 + klocal]);
                acc[t] = __builtin_amdgcn_mfma_f32_16x16x32_bf16(a, b, acc[t], 0, 0, 0);
            }
        }
    }
#pragma unroll
    for (int r = 0; r < 4; ++r) {
        int node = rowBase + kq * 4 + r;
        if (node < NN) {
            unsigned short* orow = h + (size_t)node * 128;
#pragma unroll
            for (int t = 0; t < 8; ++t)
                orow[t * 16 + ln] = f2bf(acc[t][r]);
        }
    }
}

// ---------- agg layer1: agg1[c] = relu(b1 + h[c]*dc^2 + sum h[src]*w), bf16 ----------
__global__ __launch_bounds__(256) void agg1_kernel(const unsigned short* __restrict__ h,
                                                   const float* __restrict__ dinv,
                                                   const int* __restrict__ off,
                                                   const int2* __restrict__ epair,
                                                   const void* __restrict__ b1,
                                                   unsigned short* __restrict__ outp,
                                                   const int* __restrict__ flags) {
    int lane = threadIdx.x & 63;
    int c = blockIdx.x * 4 + (threadIdx.x >> 6);
    if (c >= NN) return;
    int bf = flags[0];
    int g = lane >> 4, l = lane & 15;  // 4 edge-groups x 16 feature-lanes (8 feats each)
    float acc[8];
    float dc = dinv[c];
    if (g == 0) {
        short8 v = *(const short8*)(h + (size_t)c * 128 + l * 8);
        float w = dc * dc;
#pragma unroll
        for (int f = 0; f < 8; ++f) acc[f] = bf2f((unsigned short)v[f]) * w;
    } else {
#pragma unroll
        for (int f = 0; f < 8; ++f) acc[f] = 0.f;
    }
    int e = off[c + 1];
    for (int j = off[c] + g; j < e; j += 4) {
        int2 p = epair[j];
        int src = min(max(p.x, 0), NN - 1);
        float w = __int_as_float(p.y);
        short8 v = *(const short8*)(h + (size_t)src * 128 + l * 8);
#pragma unroll
        for (int f = 0; f < 8; ++f) acc[f] = fmaf(bf2f((unsigned short)v[f]), w, acc[f]);
    }
#pragma unroll
    for (int f = 0; f < 8; ++f) {
        acc[f] += __shfl_xor(acc[f], 16, 64);
        acc[f] += __shfl_xor(acc[f], 32, 64);
    }
    if (g == 0) {
        short8 o;
#pragma unroll
        for (int f = 0; f < 8; ++f)
            o[f] = (short)f2bf(fmaxf(acc[f] + ldf(b1, l * 8 + f, bf), 0.f));
        *(short8*)(outp + (size_t)c * 128 + l * 8) = o;
    }
}

// ---------- GEMM2 (MFMA): h2[N,64](bf16) = agg1[N,128] @ W2 ----------
__global__ __launch_bounds__(256) void gemm2_kernel(const unsigned short* __restrict__ a_,
                                                    const unsigned short* __restrict__ wt,
                                                    unsigned short* __restrict__ h2) {
    __shared__ unsigned short wl[64 * 136];  // ~17 KB
    int tid = threadIdx.x;
    for (int i = tid; i < 64 * 16; i += 256) {
        int n = i >> 4, b = i & 15;
        short8 v = *(const short8*)(wt + n * 128 + b * 8);
        *(short8*)(&wl[n * 136 + b * 8]) = v;
    }
    __syncthreads();
    int lane = tid & 63, wv = tid >> 6;
    int ln = lane & 15, kq = lane >> 4;
    int rowBase = blockIdx.x * 64 + wv * 16;
    int anode = min(rowBase + ln, NN - 1);
    const unsigned short* arow = a_ + (size_t)anode * 128;
    f32x4 acc[4];
#pragma unroll
    for (int t = 0; t < 4; ++t) acc[t] = (f32x4)0.f;
#pragma unroll
    for (int ks = 0; ks < 4; ++ks) {
        int k0 = ks * 32 + kq * 8;
        short8 a = *(const short8*)(arow + k0);
#pragma unroll
        for (int t = 0; t < 4; ++t) {
            int n = t * 16 + ln;
            short8 b = *(const short8*)(&wl[n * 136 + k0]);
            acc[t] = __builtin_amdgcn_mfma_f32_16x16x32_bf16(a, b, acc[t], 0, 0, 0);
        }
    }
#pragma unroll
    for (int r = 0; r < 4; ++r) {
        int node = rowBase + kq * 4 + r;
        if (node < NN) {
            unsigned short* orow = h2 + (size_t)node * 64;
#pragma unroll
            for (int t = 0; t < 4; ++t)
                orow[t * 16 + ln] = f2bf(acc[t][r]);
        }
    }
}

// ---------- agg layer2 fused with +b2, flag-dtyped output ----------
__global__ __launch_bounds__(256) void agg_out_kernel(const unsigned short* __restrict__ h,
                                                      const float* __restrict__ dinv,
                                                      const int* __restrict__ off,
                                                      const int2* __restrict__ epair,
                                                      const void* __restrict__ b2,
                                                      void* __restrict__ outp,
                                                      const int* __restrict__ flags) {
    int lane = threadIdx.x & 63;
    int c = blockIdx.x * 4 + (threadIdx.x >> 6);
    if (c >= NN) return;
    int bf = flags[0];
    int g = lane >> 3, l = lane & 7;  // 8 edge-groups x 8 feature-lanes (8 feats each)
    float acc[8];
    float dc = dinv[c];
    if (g == 0) {
        short8 v = *(const short8*)(h + (size_t)c * 64 + l * 8);
        float w = dc * dc;
#pragma unroll
        for (int f = 0; f < 8; ++f) acc[f] = bf2f((unsigned short)v[f]) * w;
    } else {
#pragma unroll
        for (int f = 0; f < 8; ++f) acc[f] = 0.f;
    }
    int e = off[c + 1];
    for (int j = off[c] + g; j < e; j += 8) {
        int2 p = epair[j];
        int src = min(max(p.x, 0), NN - 1);
        float w = __int_as_float(p.y);
        short8 v = *(const short8*)(h + (size_t)src * 64 + l * 8);
#pragma unroll
        for (int f = 0; f < 8; ++f) acc[f] = fmaf(bf2f((unsigned short)v[f]), w, acc[f]);
    }
#pragma unroll
    for (int f = 0; f < 8; ++f) {
        acc[f] += __shfl_xor(acc[f], 8, 64);
        acc[f] += __shfl_xor(acc[f], 16, 64);
        acc[f] += __shfl_xor(acc[f], 32, 64);
    }
    if (g == 0) {
        if (bf) {
            short8 o;
#pragma unroll
            for (int f = 0; f < 8; ++f)
                o[f] = (short)f2bf(acc[f] + ldf(b2, l * 8 + f, 1));
            *(short8*)((unsigned short*)outp + (size_t)c * 64 + l * 8) = o;
        } else {
            float* op = (float*)outp + (size_t)c * 64 + l * 8;
#pragma unroll
            for (int f = 0; f < 8; ++f)
                op[f] = acc[f] + ldf(b2, l * 8 + f, 0);
        }
    }
}

extern "C" void kernel_launch(void* const* d_in, const int* in_sizes, int n_in,
                              void* d_out, int out_size, void* d_ws, size_t ws_size,
                              hipStream_t stream) {
    const void* x  = d_in[0];
    const void* ei = d_in[1];
    const void* W1 = d_in[2];
    const void* b1 = d_in[3];
    const void* W2 = d_in[4];
    const void* b2 = d_in[5];

    const int N = NN;
    const int E = in_sizes[1] / 2;
    const int NCHUNK = (N + 1023) / 1024;

    char* ws = (char*)d_ws;
    size_t o = 0;
    auto alloc = [&](size_t bytes) { size_t r = o; o += (bytes + 255) & ~(size_t)255; return r; };
    int*   flags = (int*)(ws + alloc(256));
    int*   deg   = (int*)(ws + alloc((size_t)N * 4));
    float* dinv  = (float*)(ws + alloc((size_t)N * 4));
    int*   off   = (int*)(ws + alloc((size_t)(N + 1) * 4));
    int*   cur   = (int*)(ws + alloc((size_t)N * 4));
    int*   psum  = (int*)(ws + alloc((size_t)NCHUNK * 4));
    int2*  epair = (int2*)(ws + alloc((size_t)E * 8));
    unsigned short* w1t  = (unsigned short*)(ws + alloc(128 * 256 * 2));
    unsigned short* w2t  = (unsigned short*)(ws + alloc(64 * 128 * 2));
    unsigned short* h1   = (unsigned short*)(ws + alloc((size_t)N * 128 * 2));
    unsigned short* agg1 = (unsigned short*)(ws + alloc((size_t)N * 128 * 2));
    unsigned short* h2   = h1;  // reuse (h1 dead after agg1_kernel)

    detect_kernel<<<1, 1, 0, stream>>>((const unsigned int*)x, (const unsigned int*)ei, flags);
    zero_int_kernel<<<(N + 255) / 256, 256, 0, stream>>>(deg, N);
    hist_kernel<<<(E + 255) / 256, 256, 0, stream>>>(ei, E, deg, flags);
    scan_part_kernel<<<NCHUNK, 256, 0, stream>>>(deg, psum, dinv, N);
    scan_top_kernel<<<1, 1, 0, stream>>>(psum, NCHUNK, off, N);
    scan_final_kernel<<<NCHUNK, 256, 0, stream>>>(deg, psum, off, cur, N);
    scatter_kernel<<<(E + 255) / 256, 256, 0, stream>>>(ei, dinv, cur, epair, E, flags);
    transpose_w_kernel<<<(128 * 256 + 64 * 128 + 255) / 256, 256, 0, stream>>>(W1, W2, w1t, w2t, flags);

    gemm1_kernel<<<(N + 63) / 64, 256, 0, stream>>>(x, w1t, h1, flags);
    agg1_kernel<<<(N + 3) / 4, 256, 0, stream>>>(h1, dinv, off, epair, b1, agg1, flags);
    gemm2_kernel<<<(N + 63) / 64, 256, 0, stream>>>(agg1, w2t, h2);
    agg_out_kernel<<<(N + 3) / 4, 256, 0, stream>>>(h2, dinv, off, epair, b2, d_out, flags);
}

// Round 7
// 466.042 us; speedup vs baseline: 2.4196x; 1.0576x over previous
//
#include <hip/hip_runtime.h>

#define NN 100000

typedef __attribute__((ext_vector_type(8))) short short8;
typedef __attribute__((ext_vector_type(4))) float f32x4;

// ---------- bf16 helpers ----------
__device__ __forceinline__ float bf2f(unsigned short u) {
    union { unsigned int i; float f; } v;
    v.i = ((unsigned int)u) << 16;
    return v.f;
}
__device__ __forceinline__ unsigned short f2bf(float f) {
    unsigned int u = __float_as_uint(f);
    unsigned int r = u + 0x7fffu + ((u >> 16) & 1u);  // RNE
    return (unsigned short)(r >> 16);
}
// flags[0]=1 -> float tensors are bf16, else fp32
__device__ __forceinline__ float ldf(const void* p, int i, int bf) {
    return bf ? bf2f(((const unsigned short*)p)[i]) : ((const float*)p)[i];
}
// flags[1]=1 -> edge_index is int64, else int32
__device__ __forceinline__ int lde(const void* p, int i, int i64f) {
    return i64f ? (int)((const long long*)p)[i] : ((const int*)p)[i];
}
// load 8 consecutive float-typed input elements as bf16 short8 (flag-driven)
__device__ __forceinline__ short8 ld8bf(const void* p, size_t i, int bf) {
    if (bf) return *(const short8*)((const unsigned short*)p + i);
    const float* f = (const float*)p + i;
    f32x4 a = *(const f32x4*)f;
    f32x4 b = *(const f32x4*)(f + 4);
    short8 o;
    o[0] = (short)f2bf(a[0]); o[1] = (short)f2bf(a[1]);
    o[2] = (short)f2bf(a[2]); o[3] = (short)f2bf(a[3]);
    o[4] = (short)f2bf(b[0]); o[5] = (short)f2bf(b[1]);
    o[6] = (short)f2bf(b[2]); o[7] = (short)f2bf(b[3]);
    return o;
}

// ---------- dtype detection (single thread) — proven ----------
__global__ void detect_kernel(const unsigned int* __restrict__ xw,
                              const unsigned int* __restrict__ eiw,
                              int* __restrict__ flags) {
    if (threadIdx.x == 0 && blockIdx.x == 0) {
        int outliers = 0;
        for (int i = 0; i < 128; ++i) {
            unsigned int w = xw[i];
            int e = (int)((w >> 7) & 0xFFu);
            if (e < 100 || e > 130) outliers++;
        }
        flags[0] = (outliers < 16) ? 1 : 0;
        int zeros = 0;
        for (int i = 0; i < 64; ++i)
            if (eiw[2 * i + 1] == 0u) zeros++;
        flags[1] = (zeros >= 48) ? 1 : 0;
    }
}

// ---------- fused: degree histogram + weight transpose (independent work) ----------
__global__ void hist_tr_kernel(const void* __restrict__ ei, int E, int* __restrict__ deg,
                               const int* __restrict__ flags,
                               const void* __restrict__ w1, const void* __restrict__ w2,
                               unsigned short* __restrict__ w1t, unsigned short* __restrict__ w2t,
                               int histBlocks) {
    int bid = blockIdx.x, tid = threadIdx.x;
    if (bid < histBlocks) {
        int e = bid * 256 + tid;
        int i64f = flags[1];
        if (e < E) {
            int c = lde(ei, E + e, i64f);
            c = min(max(c, 0), NN - 1);
            atomicAdd(&deg[c], 1);
        }
    } else {
        int bf = flags[0];
        int i = (bid - histBlocks) * 256 + tid;
        if (i < 128 * 256) {
            int n = i >> 8, k = i & 255;
            w1t[n * 256 + k] = f2bf(ldf(w1, k * 128 + n, bf));
        } else if (i < 128 * 256 + 64 * 128) {
            int j = i - 128 * 256;
            int n = j >> 7, k = j & 127;
            w2t[n * 128 + k] = f2bf(ldf(w2, k * 64 + n, bf));
        }
    }
}

// ---------- parallel scan: 98 chunks of 1024 (dinv fused in) ----------
__global__ void scan_part_kernel(const int* __restrict__ deg, int* __restrict__ psum,
                                 float* __restrict__ dinv, int n) {
    __shared__ int s[256];
    int tid = threadIdx.x;
    int base = blockIdx.x * 1024 + tid * 4;
    int t = 0;
#pragma unroll
    for (int q = 0; q < 4; ++q) {
        if (base + q < n) {
            int d = deg[base + q];
            t += d;
            dinv[base + q] = rsqrtf((float)(d + 1));
        }
    }
    s[tid] = t;
    __syncthreads();
    for (int o = 128; o > 0; o >>= 1) {
        if (tid < o) s[tid] += s[tid + o];
        __syncthreads();
    }
    if (tid == 0) psum[blockIdx.x] = s[0];
}

__global__ void scan_top_kernel(int* __restrict__ psum, int nchunks, int* __restrict__ off, int n) {
    if (threadIdx.x == 0) {
        int acc = 0;
        for (int i = 0; i < nchunks; ++i) {
            int v = psum[i];
            psum[i] = acc;
            acc += v;
        }
        off[n] = acc;
    }
}

__global__ void scan_final_kernel(const int* __restrict__ deg, const int* __restrict__ psum,
                                  int* __restrict__ off, int* __restrict__ cur, int n) {
    __shared__ int s[256];
    int tid = threadIdx.x;
    int idx = blockIdx.x * 1024 + tid * 4;
    int v0 = (idx + 0 < n) ? deg[idx + 0] : 0;
    int v1 = (idx + 1 < n) ? deg[idx + 1] : 0;
    int v2 = (idx + 2 < n) ? deg[idx + 2] : 0;
    int v3 = (idx + 3 < n) ? deg[idx + 3] : 0;
    int tsum = v0 + v1 + v2 + v3;
    s[tid] = tsum;
    __syncthreads();
    for (int o = 1; o < 256; o <<= 1) {
        int t = (tid >= o) ? s[tid - o] : 0;
        __syncthreads();
        s[tid] += t;
        __syncthreads();
    }
    int p = psum[blockIdx.x] + s[tid] - tsum;
    if (idx + 0 < n) { off[idx + 0] = p; cur[idx + 0] = p; } p += v0;
    if (idx + 1 < n) { off[idx + 1] = p; cur[idx + 1] = p; } p += v1;
    if (idx + 2 < n) { off[idx + 2] = p; cur[idx + 2] = p; } p += v2;
    if (idx + 3 < n) { off[idx + 3] = p; cur[idx + 3] = p; }
}

// ---------- fused: CSR scatter (latency-bound) + GEMM1 (MFMA-bound) ----------
// Independent chains; gemm blocks interleaved every 5th block for co-residency.
__global__ __launch_bounds__(256) void sg1_kernel(const void* __restrict__ ei,
                                                  const float* __restrict__ dinv,
                                                  int* __restrict__ cur, int2* __restrict__ epair,
                                                  int E, const int* __restrict__ flags,
                                                  const void* __restrict__ x,
                                                  const unsigned short* __restrict__ wt,
                                                  unsigned short* __restrict__ h, int GB) {
    __shared__ unsigned short wl[128 * 136];  // ~34 KB (gemm path only)
    int bid = blockIdx.x, tid = threadIdx.x;
    bool isG = ((bid % 5) == 0) && (bid / 5 < GB);
    if (!isG) {
        // -------- scatter path --------
        int sIdx = bid - min((bid + 4) / 5, GB);
        int e = sIdx * 256 + tid;
        int i64f = flags[1];
        if (e < E) {
            int r = lde(ei, e, i64f);
            int c = lde(ei, E + e, i64f);
            r = min(max(r, 0), NN - 1);
            c = min(max(c, 0), NN - 1);
            int pos = atomicAdd(&cur[c], 1);
            epair[pos] = make_int2(r, __float_as_int(dinv[r] * dinv[c]));
        }
        return;
    }
    // -------- gemm1 path (identical to proven gemm1_kernel, block idx = bid/5) --------
    int gb = bid / 5;
    int bf = flags[0];
    int lane = tid & 63, wv = tid >> 6;
    int ln = lane & 15, kq = lane >> 4;
    int rowBase = gb * 64 + wv * 16;
    int anode = min(rowBase + ln, NN - 1);
    size_t abase = (size_t)anode * 256;
    f32x4 acc[8];
#pragma unroll
    for (int t = 0; t < 8; ++t) acc[t] = (f32x4)0.f;

    for (int half = 0; half < 2; ++half) {
        __syncthreads();
        for (int i = tid; i < 128 * 16; i += 256) {
            int n = i >> 4, b = i & 15;
            short8 v = *(const short8*)(wt + n * 256 + half * 128 + b * 8);
            *(short8*)(&wl[n * 136 + b * 8]) = v;
        }
        __syncthreads();
#pragma unroll
        for (int ks = 0; ks < 4; ++ks) {
            int klocal = ks * 32 + kq * 8;
            short8 a = ld8bf(x, abase + half * 128 + klocal, bf);
#pragma unroll
            for (int t = 0; t < 8; ++t) {
                int n = t * 16 + ln;
                short8 b = *(const short8*)(&wl[n * 136 + klocal]);
                acc[t] = __builtin_amdgcn_mfma_f32_16x16x32_bf16(a, b, acc[t], 0, 0, 0);
            }
        }
    }
#pragma unroll
    for (int r = 0; r < 4; ++r) {
        int node = rowBase + kq * 4 + r;
        if (node < NN) {
            unsigned short* orow = h + (size_t)node * 128;
#pragma unroll
            for (int t = 0; t < 8; ++t)
                orow[t * 16 + ln] = f2bf(acc[t][r]);
        }
    }
}

// ---------- agg layer1 (unroll x2 for MLP): relu(b1 + h[c]*dc^2 + sum h[src]*w) ----------
__global__ __launch_bounds__(256) void agg1_kernel(const unsigned short* __restrict__ h,
                                                   const float* __restrict__ dinv,
                                                   const int* __restrict__ off,
                                                   const int2* __restrict__ epair,
                                                   const void* __restrict__ b1,
                                                   unsigned short* __restrict__ outp,
                                                   const int* __restrict__ flags) {
    int lane = threadIdx.x & 63;
    int c = blockIdx.x * 4 + (threadIdx.x >> 6);
    if (c >= NN) return;
    int bf = flags[0];
    int g = lane >> 4, l = lane & 15;  // 4 edge-groups x 16 feature-lanes
    float acc[8];
    float dc = dinv[c];
    if (g == 0) {
        short8 v = *(const short8*)(h + (size_t)c * 128 + l * 8);
        float w = dc * dc;
#pragma unroll
        for (int f = 0; f < 8; ++f) acc[f] = bf2f((unsigned short)v[f]) * w;
    } else {
#pragma unroll
        for (int f = 0; f < 8; ++f) acc[f] = 0.f;
    }
    int e = off[c + 1];
    int j = off[c] + g;
    for (; j + 4 < e; j += 8) {  // two edges per iteration per group
        int2 p0 = epair[j];
        int2 p1 = epair[j + 4];
        int s0 = min(max(p0.x, 0), NN - 1);
        int s1 = min(max(p1.x, 0), NN - 1);
        float w0 = __int_as_float(p0.y);
        float w1 = __int_as_float(p1.y);
        short8 v0 = *(const short8*)(h + (size_t)s0 * 128 + l * 8);
        short8 v1 = *(const short8*)(h + (size_t)s1 * 128 + l * 8);
#pragma unroll
        for (int f = 0; f < 8; ++f) {
            acc[f] = fmaf(bf2f((unsigned short)v0[f]), w0, acc[f]);
            acc[f] = fmaf(bf2f((unsigned short)v1[f]), w1, acc[f]);
        }
    }
    if (j < e) {
        int2 p = epair[j];
        int src = min(max(p.x, 0), NN - 1);
        float w = __int_as_float(p.y);
        short8 v = *(const short8*)(h + (size_t)src * 128 + l * 8);
#pragma unroll
        for (int f = 0; f < 8; ++f) acc[f] = fmaf(bf2f((unsigned short)v[f]), w, acc[f]);
    }
#pragma unroll
    for (int f = 0; f < 8; ++f) {
        acc[f] += __shfl_xor(acc[f], 16, 64);
        acc[f] += __shfl_xor(acc[f], 32, 64);
    }
    if (g == 0) {
        short8 o;
#pragma unroll
        for (int f = 0; f < 8; ++f)
            o[f] = (short)f2bf(fmaxf(acc[f] + ldf(b1, l * 8 + f, bf), 0.f));
        *(short8*)(outp + (size_t)c * 128 + l * 8) = o;
    }
}

// ---------- GEMM2 (MFMA): h2[N,64](bf16) = agg1[N,128] @ W2 ----------
__global__ __launch_bounds__(256) void gemm2_kernel(const unsigned short* __restrict__ a_,
                                                    const unsigned short* __restrict__ wt,
                                                    unsigned short* __restrict__ h2) {
    __shared__ unsigned short wl[64 * 136];  // ~17 KB
    int tid = threadIdx.x;
    for (int i = tid; i < 64 * 16; i += 256) {
        int n = i >> 4, b = i & 15;
        short8 v = *(const short8*)(wt + n * 128 + b * 8);
        *(short8*)(&wl[n * 136 + b * 8]) = v;
    }
    __syncthreads();
    int lane = tid & 63, wv = tid >> 6;
    int ln = lane & 15, kq = lane >> 4;
    int rowBase = blockIdx.x * 64 + wv * 16;
    int anode = min(rowBase + ln, NN - 1);
    const unsigned short* arow = a_ + (size_t)anode * 128;
    f32x4 acc[4];
#pragma unroll
    for (int t = 0; t < 4; ++t) acc[t] = (f32x4)0.f;
#pragma unroll
    for (int ks = 0; ks < 4; ++ks) {
        int k0 = ks * 32 + kq * 8;
        short8 a = *(const short8*)(arow + k0);
#pragma unroll
        for (int t = 0; t < 4; ++t) {
            int n = t * 16 + ln;
            short8 b = *(const short8*)(&wl[n * 136 + k0]);
            acc[t] = __builtin_amdgcn_mfma_f32_16x16x32_bf16(a, b, acc[t], 0, 0, 0);
        }
    }
#pragma unroll
    for (int r = 0; r < 4; ++r) {
        int node = rowBase + kq * 4 + r;
        if (node < NN) {
            unsigned short* orow = h2 + (size_t)node * 64;
#pragma unroll
            for (int t = 0; t < 4; ++t)
                orow[t * 16 + ln] = f2bf(acc[t][r]);
        }
    }
}

// ---------- agg layer2 (unroll x2) fused with +b2, flag-dtyped output ----------
__global__ __launch_bounds__(256) void agg_out_kernel(const unsigned short* __restrict__ h,
                                                      const float* __restrict__ dinv,
                                                      const int* __restrict__ off,
                                                      const int2* __restrict__ epair,
                                                      const void* __restrict__ b2,
                                                      void* __restrict__ outp,
                                                      const int* __restrict__ flags) {
    int lane = threadIdx.x & 63;
    int c = blockIdx.x * 4 + (threadIdx.x >> 6);
    if (c >= NN) return;
    int bf = flags[0];
    int g = lane >> 3, l = lane & 7;  // 8 edge-groups x 8 feature-lanes
    float acc[8];
    float dc = dinv[c];
    if (g == 0) {
        short8 v = *(const short8*)(h + (size_t)c * 64 + l * 8);
        float w = dc * dc;
#pragma unroll
        for (int f = 0; f < 8; ++f) acc[f] = bf2f((unsigned short)v[f]) * w;
    } else {
#pragma unroll
        for (int f = 0; f < 8; ++f) acc[f] = 0.f;
    }
    int e = off[c + 1];
    int j = off[c] + g;
    for (; j + 8 < e; j += 16) {  // two edges per iteration per group
        int2 p0 = epair[j];
        int2 p1 = epair[j + 8];
        int s0 = min(max(p0.x, 0), NN - 1);
        int s1 = min(max(p1.x, 0), NN - 1);
        float w0 = __int_as_float(p0.y);
        float w1 = __int_as_float(p1.y);
        short8 v0 = *(const short8*)(h + (size_t)s0 * 64 + l * 8);
        short8 v1 = *(const short8*)(h + (size_t)s1 * 64 + l * 8);
#pragma unroll
        for (int f = 0; f < 8; ++f) {
            acc[f] = fmaf(bf2f((unsigned short)v0[f]), w0, acc[f]);
            acc[f] = fmaf(bf2f((unsigned short)v1[f]), w1, acc[f]);
        }
    }
    if (j < e) {
        int2 p = epair[j];
        int src = min(max(p.x, 0), NN - 1);
        float w = __int_as_float(p.y);
        short8 v = *(const short8*)(h + (size_t)src * 64 + l * 8);
#pragma unroll
        for (int f = 0; f < 8; ++f) acc[f] = fmaf(bf2f((unsigned short)v[f]), w, acc[f]);
    }
#pragma unroll
    for (int f = 0; f < 8; ++f) {
        acc[f] += __shfl_xor(acc[f], 8, 64);
        acc[f] += __shfl_xor(acc[f], 16, 64);
        acc[f] += __shfl_xor(acc[f], 32, 64);
    }
    if (g == 0) {
        if (bf) {
            short8 o;
#pragma unroll
            for (int f = 0; f < 8; ++f)
                o[f] = (short)f2bf(acc[f] + ldf(b2, l * 8 + f, 1));
            *(short8*)((unsigned short*)outp + (size_t)c * 64 + l * 8) = o;
        } else {
            float* op = (float*)outp + (size_t)c * 64 + l * 8;
#pragma unroll
            for (int f = 0; f < 8; ++f)
                op[f] = acc[f] + ldf(b2, l * 8 + f, 0);
        }
    }
}

extern "C" void kernel_launch(void* const* d_in, const int* in_sizes, int n_in,
                              void* d_out, int out_size, void* d_ws, size_t ws_size,
                              hipStream_t stream) {
    const void* x  = d_in[0];
    const void* ei = d_in[1];
    const void* W1 = d_in[2];
    const void* b1 = d_in[3];
    const void* W2 = d_in[4];
    const void* b2 = d_in[5];

    const int N = NN;
    const int E = in_sizes[1] / 2;
    const int NCHUNK = (N + 1023) / 1024;
    const int SB = (E + 255) / 256;          // scatter blocks
    const int GB = (N + 63) / 64;            // gemm1 blocks
    const int TB = (128 * 256 + 64 * 128 + 255) / 256;  // transpose blocks

    char* ws = (char*)d_ws;
    size_t o = 0;
    auto alloc = [&](size_t bytes) { size_t r = o; o += (bytes + 255) & ~(size_t)255; return r; };
    int*   flags = (int*)(ws + alloc(256));
    int*   deg   = (int*)(ws + alloc((size_t)N * 4));
    float* dinv  = (float*)(ws + alloc((size_t)N * 4));
    int*   off   = (int*)(ws + alloc((size_t)(N + 1) * 4));
    int*   cur   = (int*)(ws + alloc((size_t)N * 4));
    int*   psum  = (int*)(ws + alloc((size_t)NCHUNK * 4));
    int2*  epair = (int2*)(ws + alloc((size_t)E * 8));
    unsigned short* w1t  = (unsigned short*)(ws + alloc(128 * 256 * 2));
    unsigned short* w2t  = (unsigned short*)(ws + alloc(64 * 128 * 2));
    unsigned short* h1   = (unsigned short*)(ws + alloc((size_t)N * 128 * 2));
    unsigned short* agg1 = (unsigned short*)(ws + alloc((size_t)N * 128 * 2));
    unsigned short* h2   = h1;  // reuse (h1 dead after agg1_kernel)

    detect_kernel<<<1, 1, 0, stream>>>((const unsigned int*)x, (const unsigned int*)ei, flags);
    hipMemsetAsync(deg, 0, (size_t)N * 4, stream);
    hist_tr_kernel<<<SB + TB, 256, 0, stream>>>(ei, E, deg, flags, W1, W2, w1t, w2t, SB);
    scan_part_kernel<<<NCHUNK, 256, 0, stream>>>(deg, psum, dinv, N);
    scan_top_kernel<<<1, 1, 0, stream>>>(psum, NCHUNK, off, N);
    scan_final_kernel<<<NCHUNK, 256, 0, stream>>>(deg, psum, off, cur, N);
    sg1_kernel<<<GB + SB, 256, 0, stream>>>(ei, dinv, cur, epair, E, flags, x, w1t, h1, GB);
    agg1_kernel<<<(N + 3) / 4, 256, 0, stream>>>(h1, dinv, off, epair, b1, agg1, flags);
    gemm2_kernel<<<GB, 256, 0, stream>>>(agg1, w2t, h2);
    agg_out_kernel<<<(N + 3) / 4, 256, 0, stream>>>(h2, dinv, off, epair, b2, d_out, flags);
}